// Round 6
// baseline (857.437 us; speedup 1.0000x reference)
//
#include <hip/hip_runtime.h>
#include <hip/hip_bf16.h>
#include <hip/hip_fp8.h>

typedef int i32x8 __attribute__((ext_vector_type(8)));
typedef int i32x4 __attribute__((ext_vector_type(4)));
typedef float f32x4 __attribute__((ext_vector_type(4)));
typedef unsigned char uchar_t;

constexpr int NB = 32768;   // batch rows
constexpr int D1 = 1024;    // K
constexpr int D2 = 4096;    // N
constexpr float BETA_LOG2E = 14.4269504088896340736f; // 10 * log2(e)
constexpr float SCALE_A = 16.0f;        // g1 pre-scale into e4m3 sweet range
constexpr float SCALE_B = 8192.0f;      // dW pre-scale (dW ~ 0.003*N)
constexpr float INV_SCALE = 1.0f / (16.0f * 8192.0f);  // 2^-17

__device__ __forceinline__ uchar_t f32_to_fp8(float f) {
  __hip_fp8_e4m3 q(f);                  // OCP e4m3fn, RNE+satfinite
  return (uchar_t)q.__x;
}

__device__ __forceinline__ void async_copy16(const void* g, void* l) {
  __builtin_amdgcn_global_load_lds(
      (const __attribute__((address_space(1))) void*)g,
      (__attribute__((address_space(3))) void*)l, 16, 0, 0);
}

// ---- 1. column stats of W: sq[j] += sum_k W^2 ; colsum[j] += sum_k W ----
__global__ void colstats(const float* __restrict__ W, float* __restrict__ sq,
                         float* __restrict__ colsum) {
  int j = blockIdx.x * 256 + threadIdx.x;   // gridDim.x = 16
  int k0 = blockIdx.y * 64;                 // gridDim.y = 16
  float a = 0.f, b = 0.f;
#pragma unroll 8
  for (int k = 0; k < 64; ++k) {
    float w = W[(size_t)(k0 + k) * D2 + j];
    a += w * w; b += w;
  }
  atomicAdd(&sq[j], a);
  atomicAdd(&colsum[j], b);
}

// ---- 2. mean-subtracted normalize + transpose to fp8:
// mu[j] = colsum[j]*inv/1024; B8t[j][k] = fp8((W[k][j]*inv - mu[j]) * SCALE_B)
__global__ void convert_b(const float* __restrict__ W, const float* __restrict__ sq,
                          const float* __restrict__ colsum,
                          uchar_t* __restrict__ B8t, float* __restrict__ mu) {
  __shared__ float tile[64][65];
  int t = threadIdx.x;                 // 256
  int j0 = blockIdx.x * 64;            // gridDim.x = 64
  int k0 = blockIdx.y * 64;            // gridDim.y = 16
  int c = t & 63, r4 = t >> 6;
#pragma unroll
  for (int s = 0; s < 16; ++s) {
    int k = s * 4 + r4;
    tile[k][c] = W[(size_t)(k0 + k) * D2 + j0 + c];
  }
  __syncthreads();
#pragma unroll
  for (int s = 0; s < 16; ++s) {
    int jj = s * 4 + r4;
    float inv = 1.0f / sqrtf(sq[j0 + jj]);
    float muj = colsum[j0 + jj] * inv * (1.0f / 1024.0f);
    if (k0 == 0 && c == 0) mu[j0 + jj] = muj;
    float dw = tile[c][jj] * inv - muj;
    B8t[(size_t)(j0 + jj) * D1 + k0 + c] = f32_to_fp8(dw * SCALE_B);
  }
}

// ---- 3. g1 fp32 -> fp8 (x16) + row sums. Wave-per-row, grid-stride. ----
__global__ __launch_bounds__(256)
void convert_a(const float* __restrict__ g1, uchar_t* __restrict__ A8,
               float* __restrict__ S) {
  const int lane = threadIdx.x & 63;
  const int gw = (blockIdx.x * 256 + threadIdx.x) >> 6;  // 8192 waves
  for (int row = gw; row < NB; row += 8192) {
    const float* src = g1 + (size_t)row * D1 + lane * 16;
    float v[16];
    *(float4*)(v)      = ((const float4*)src)[0];
    *(float4*)(v + 4)  = ((const float4*)src)[1];
    *(float4*)(v + 8)  = ((const float4*)src)[2];
    *(float4*)(v + 12) = ((const float4*)src)[3];
    float sum = 0.f;
    union { uchar_t b[16]; uint4 u; } o;
#pragma unroll
    for (int j = 0; j < 16; ++j) { sum += v[j]; o.b[j] = f32_to_fp8(v[j] * SCALE_A); }
    *(uint4*)(A8 + (size_t)row * D1 + lane * 16) = o.u;
#pragma unroll
    for (int m = 1; m < 64; m <<= 1) sum += __shfl_xor(sum, m, 64);
    if (lane == 0) S[row] = sum;
  }
}

// ---- 4. fused fp8 GEMM + exp-sum, 256x256 tile, 512 thr = 8 waves (2M x 4N),
// per-wave 128x64 out, counted-vmcnt 3-phase schedule (correctness proven
// R2-R4; passed 3x).
//
// R6 GRID ORDER: x = ROW (fast axis), y = col. Why: per-wave 64x64 tiles
// (R0/R5 128^2 geometry) are LDS-issue-bound -- 12 ds_read_b128 (~144cy) per
// 8 MFMA (~69cy) caps MfmaUtil at ~25% (measured 22-26% across R0/R5, schedule
// changes null). 128x64 per-wave tiles need the 256^2 block, which thrashed L2
// under three XCD-mapping guesses (R2-R4: FETCH ~1GB, zero reuse, mapping is
// undefined). Row-fast order is ROBUST TO ANY DISPATCH POLICY: any contiguous
// block window spans <=2 col-panels -> B working set <=512 KiB per XCD,
// always L2-hot; A streams once per col-panel (16x32MB = 512MB, L3-resident
// at ~3.5TB/s). Expected: FETCH ~520MB (deliberate streaming), gemm ~150us.
__global__ __launch_bounds__(512, 2)
void gemm_expsum(const uchar_t* __restrict__ A8, const uchar_t* __restrict__ B8t,
                 const float* __restrict__ S, const float* __restrict__ mu,
                 float* __restrict__ s) {
  __shared__ __align__(16) uchar_t As[2 * 256 * 128];  // 64 KiB
  __shared__ __align__(16) uchar_t Bs[2 * 256 * 128];  // 64 KiB

  const int row0 = blockIdx.x * 256;   // gridDim.x = 128 (FAST: stream A rows)
  const int col0 = blockIdx.y * 256;   // gridDim.y = 16  (B panel stays hot)

  const int t = threadIdx.x;
  const int lane = t & 63;
  const int wave = t >> 6;
  const int wm = (wave >> 2) * 128;    // 2 M-groups
  const int wn = (wave & 3) * 64;      // 4 N-groups
  const int llo = lane & 15, lhi = lane >> 4;

  f32x4 acc[8][4] = {};

  // staging geometry: thread t -> local row r = t>>3, seg = t&7; fetches
  // global segment seg^(r&7) so the LINEAR LDS write lands swizzled.
  const int r   = t >> 3;
  const int rB  = ((r >> 5) << 6) + (r & 31);   // B-unit base rows {0-31,64-95}
  const int seg = t & 7;
  const int swz = seg ^ (r & 7);
  const uchar_t* gA = A8  + (size_t)(row0 + r ) * D1 + swz * 16;
  const uchar_t* gB = B8t + (size_t)(col0 + rB) * D1 + swz * 16;
  uchar_t* lA = As + r  * 128 + seg * 16;
  uchar_t* lB = Bs + rB * 128 + seg * 16;

#define ISSUE_A0(kt, bo) { async_copy16(gA + (kt),              lA + (bo)); \
                           async_copy16(gA + (kt) + 128 * 1024, lA + (bo) + 128 * 128); }
#define ISSUE_B0(kt, bo) { async_copy16(gB + (kt),              lB + (bo)); \
                           async_copy16(gB + (kt) + 128 * 1024, lB + (bo) + 128 * 128); }
#define ISSUE_B1(kt, bo) { async_copy16(gB + (kt) +  32 * 1024, lB + (bo) +  32 * 128); \
                           async_copy16(gB + (kt) + 160 * 1024, lB + (bo) + 160 * 128); }
#define ISSUE_A1(kt, bo) { async_copy16(gA + (kt) +  64 * 1024, lA + (bo) +  64 * 128); \
                           async_copy16(gA + (kt) + 192 * 1024, lA + (bo) + 192 * 128); }

  // lane's fragment k-window lhi*32..+31 = two 16B segs at swizzled slots
  const int sw0 = ((lhi * 2 + 0) ^ (llo & 7)) * 16;
  const int sw1 = ((lhi * 2 + 1) ^ (llo & 7)) * 16;

  // prologue: tile 0 into buf 0 (issue order defines vmcnt age order)
  ISSUE_A0(0, 0); ISSUE_B0(0, 0); ISSUE_B1(0, 0); ISSUE_A1(0, 0);
  asm volatile("s_waitcnt vmcnt(4)" ::: "memory");   // A0,B0 landed; B1,A1 fly
  __builtin_amdgcn_s_barrier();

  for (int T = 0; T < 8; ++T) {
    const int p = T & 1;
    const int kt1 = ((T + 1) & 7) * 128;   // wraps to 0 on last iter (dummy)
    const int bo1 = (p ^ 1) * 32768;
    const uchar_t* baseA = As + p * 32768;
    const uchar_t* baseB = Bs + p * 32768;
    i32x8 af[4], bq[4];

    // ---------- P1: mh=0, nh=0 ----------
    ISSUE_A0(kt1, bo1); ISSUE_B0(kt1, bo1);
#pragma unroll
    for (int q = 0; q < 4; ++q) {
      const uchar_t* a = baseA + (wm + q * 16 + llo) * 128;
      i32x4 h0 = *(const i32x4*)(a + sw0);
      i32x4 h1 = *(const i32x4*)(a + sw1);
      af[q] = __builtin_shufflevector(h0, h1, 0, 1, 2, 3, 4, 5, 6, 7);
    }
#pragma unroll
    for (int j = 0; j < 2; ++j) {
      const uchar_t* b = baseB + (wn + j * 16 + llo) * 128;
      i32x4 h0 = *(const i32x4*)(b + sw0);
      i32x4 h1 = *(const i32x4*)(b + sw1);
      bq[j] = __builtin_shufflevector(h0, h1, 0, 1, 2, 3, 4, 5, 6, 7);
    }
    __builtin_amdgcn_s_setprio(1);
#pragma unroll
    for (int q = 0; q < 4; ++q)
#pragma unroll
      for (int j = 0; j < 2; ++j)
        acc[q][j] = __builtin_amdgcn_mfma_scale_f32_16x16x128_f8f6f4(
            af[q], bq[j], acc[q][j], 0, 0, 0, 127, 0, 127);
    __builtin_amdgcn_s_setprio(0);
    asm volatile("s_waitcnt vmcnt(6)" ::: "memory");  // T.B1 landed
    __builtin_amdgcn_s_barrier();

    // ---------- P2: mh=0, nh=1 ----------
    ISSUE_B1(kt1, bo1);
#pragma unroll
    for (int j = 0; j < 2; ++j) {
      const uchar_t* b = baseB + (wn + (2 + j) * 16 + llo) * 128;
      i32x4 h0 = *(const i32x4*)(b + sw0);
      i32x4 h1 = *(const i32x4*)(b + sw1);
      bq[2 + j] = __builtin_shufflevector(h0, h1, 0, 1, 2, 3, 4, 5, 6, 7);
    }
    __builtin_amdgcn_s_setprio(1);
#pragma unroll
    for (int q = 0; q < 4; ++q)
#pragma unroll
      for (int j = 0; j < 2; ++j)
        acc[q][2 + j] = __builtin_amdgcn_mfma_scale_f32_16x16x128_f8f6f4(
            af[q], bq[2 + j], acc[q][2 + j], 0, 0, 0, 127, 0, 127);
    __builtin_amdgcn_s_setprio(0);
    asm volatile("s_waitcnt vmcnt(6)" ::: "memory");  // T.A1 landed
    __builtin_amdgcn_s_barrier();

    // ---------- P3: mh=1, all nh ----------
    ISSUE_A1(kt1, bo1);
#pragma unroll
    for (int q = 0; q < 4; ++q) {
      const uchar_t* a = baseA + (wm + 64 + q * 16 + llo) * 128;
      i32x4 h0 = *(const i32x4*)(a + sw0);
      i32x4 h1 = *(const i32x4*)(a + sw1);
      af[q] = __builtin_shufflevector(h0, h1, 0, 1, 2, 3, 4, 5, 6, 7);
    }
    __builtin_amdgcn_s_setprio(1);
#pragma unroll
    for (int q = 0; q < 4; ++q)
#pragma unroll
      for (int j = 0; j < 4; ++j)
        acc[4 + q][j] = __builtin_amdgcn_mfma_scale_f32_16x16x128_f8f6f4(
            af[q], bq[j], acc[4 + q][j], 0, 0, 0, 127, 0, 127);
    __builtin_amdgcn_s_setprio(0);
    asm volatile("s_waitcnt vmcnt(4)" ::: "memory");  // T1.{A0,B0} landed; 4 fly
    __builtin_amdgcn_s_barrier();
  }
#undef ISSUE_A0
#undef ISSUE_B0
#undef ISSUE_B1
#undef ISSUE_A1

  // epilogue: x2 = mu_j*S_b + acc*2^-17; per-row sum of exp2(x2*beta*log2e).
  // C/D layout (16x16): col = lane&15, row = (lane>>4)*4 + reg.
  float muv[4];
#pragma unroll
  for (int ni = 0; ni < 4; ++ni) muv[ni] = mu[col0 + wn + ni * 16 + llo];

#pragma unroll
  for (int mi = 0; mi < 8; ++mi) {
    const int row = row0 + wm + mi * 16 + lhi * 4;
    float4 sv = *(const float4*)(S + row);
    float sarr[4] = {sv.x, sv.y, sv.z, sv.w};
    float rs[4];
#pragma unroll
    for (int rr = 0; rr < 4; ++rr) {
      float v = 0.f;
#pragma unroll
      for (int ni = 0; ni < 4; ++ni) {
        float x2 = fmaf(acc[mi][ni][rr], INV_SCALE, muv[ni] * sarr[rr]);
        v += exp2f(x2 * BETA_LOG2E);
      }
      rs[rr] = v;
    }
#pragma unroll
    for (int m = 1; m < 16; m <<= 1) {
#pragma unroll
      for (int rr = 0; rr < 4; ++rr)
        rs[rr] += __shfl_xor(rs[rr], m, 64);
    }
    if (llo == 0) {
#pragma unroll
      for (int rr = 0; rr < 4; ++rr)
        atomicAdd(&s[row + rr], rs[rr]);
    }
  }
}

// ---- 5. out[b] = -(1/beta) * log(s[b]) ----
__global__ void finish_kernel(const float* __restrict__ s, float* __restrict__ out) {
  int b = blockIdx.x * 256 + threadIdx.x;
  out[b] = -0.1f * logf(s[b]);
}

extern "C" void kernel_launch(void* const* d_in, const int* in_sizes, int n_in,
                              void* d_out, int out_size, void* d_ws, size_t ws_size,
                              hipStream_t stream) {
  const float* g1 = (const float*)d_in[0];
  const float* W  = (const float*)d_in[1];
  float* out = (float*)d_out;

  char* ws = (char*)d_ws;
  float* s       = (float*)ws;                    // 32768*4 = 131072
  float* sq      = (float*)(ws + 131072);         // 4096*4
  float* colsum  = (float*)(ws + 147456);         // 4096*4
  float* mu      = (float*)(ws + 163840);         // 4096*4
  float* S       = (float*)(ws + 180224);         // 32768*4
  uchar_t* A8    = (uchar_t*)(ws + 311296);       // 32 MiB
  uchar_t* B8t   = (uchar_t*)(ws + 311296 + 33554432);  // 4 MiB

  hipMemsetAsync(ws, 0, 180224, stream);  // zero s, sq, colsum

  colstats<<<dim3(16, 16), 256, 0, stream>>>(W, sq, colsum);
  convert_b<<<dim3(64, 16), 256, 0, stream>>>(W, sq, colsum, B8t, mu);
  convert_a<<<dim3(2048), 256, 0, stream>>>(g1, A8, S);
  gemm_expsum<<<dim3(128, 16), 512, 0, stream>>>(A8, B8t, S, mu, s);
  finish_kernel<<<dim3(128), 256, 0, stream>>>(s, out);
}

// Round 7
// 421.989 us; speedup vs baseline: 2.0319x; 2.0319x over previous
//
#include <hip/hip_runtime.h>
#include <hip/hip_bf16.h>
#include <hip/hip_fp8.h>

typedef int i32x8 __attribute__((ext_vector_type(8)));
typedef int i32x4 __attribute__((ext_vector_type(4)));
typedef float f32x4 __attribute__((ext_vector_type(4)));
typedef unsigned char uchar_t;

constexpr int NB = 32768;   // batch rows
constexpr int D1 = 1024;    // K
constexpr int D2 = 4096;    // N
constexpr float BETA_LOG2E = 14.4269504088896340736f; // 10 * log2(e)
constexpr float SCALE_A = 16.0f;        // g1 pre-scale into e4m3 sweet range
constexpr float SCALE_B = 8192.0f;      // dW pre-scale (dW ~ 0.003*N)
constexpr float INV_SCALE = 1.0f / (16.0f * 8192.0f);  // 2^-17

// HW packed f32->fp8 e4m3 (RNE, saturating) -- replaces the __hip_fp8_e4m3
// constructor's multi-instruction emulation (~20 VALU ops -> 1).
__device__ __forceinline__ uchar_t f32_to_fp8(float f) {
  return (uchar_t)(__builtin_amdgcn_cvt_pk_fp8_f32(f, f, 0, false) & 0xff);
}

__device__ __forceinline__ void async_copy16(const void* g, void* l) {
  __builtin_amdgcn_global_load_lds(
      (const __attribute__((address_space(1))) void*)g,
      (__attribute__((address_space(3))) void*)l, 16, 0, 0);
}

// ---- 1. FUSED: g1 fp32->fp8 (x16) + row sums (blocks 0..2047)  AND
//               column stats of W (blocks 2048..2303).
// Independent data; block-range split overlaps the 16MB stats read with the
// 128MB g1 stream and saves a dispatch.
__global__ __launch_bounds__(256)
void prep_fused(const float* __restrict__ g1, uchar_t* __restrict__ A8,
                float* __restrict__ S, const float* __restrict__ W,
                float* __restrict__ sq, float* __restrict__ colsum) {
  if (blockIdx.x < 2048) {
    // ---- convert_a: wave-per-row, grid-stride (8192 waves) ----
    const int lane = threadIdx.x & 63;
    const int gw = (blockIdx.x * 256 + threadIdx.x) >> 6;
    for (int row = gw; row < NB; row += 8192) {
      const float* src = g1 + (size_t)row * D1 + lane * 16;
      float v[16];
      *(float4*)(v)      = ((const float4*)src)[0];
      *(float4*)(v + 4)  = ((const float4*)src)[1];
      *(float4*)(v + 8)  = ((const float4*)src)[2];
      *(float4*)(v + 12) = ((const float4*)src)[3];
      float sum = 0.f;
      uint4 o;
      unsigned w;
#pragma unroll
      for (int j = 0; j < 16; ++j) sum += v[j];
      w = __builtin_amdgcn_cvt_pk_fp8_f32(v[0] * SCALE_A, v[1] * SCALE_A, 0, false);
      w = __builtin_amdgcn_cvt_pk_fp8_f32(v[2] * SCALE_A, v[3] * SCALE_A, w, true);
      o.x = w;
      w = __builtin_amdgcn_cvt_pk_fp8_f32(v[4] * SCALE_A, v[5] * SCALE_A, 0, false);
      w = __builtin_amdgcn_cvt_pk_fp8_f32(v[6] * SCALE_A, v[7] * SCALE_A, w, true);
      o.y = w;
      w = __builtin_amdgcn_cvt_pk_fp8_f32(v[8] * SCALE_A, v[9] * SCALE_A, 0, false);
      w = __builtin_amdgcn_cvt_pk_fp8_f32(v[10] * SCALE_A, v[11] * SCALE_A, w, true);
      o.z = w;
      w = __builtin_amdgcn_cvt_pk_fp8_f32(v[12] * SCALE_A, v[13] * SCALE_A, 0, false);
      w = __builtin_amdgcn_cvt_pk_fp8_f32(v[14] * SCALE_A, v[15] * SCALE_A, w, true);
      o.w = w;
      *(uint4*)(A8 + (size_t)row * D1 + lane * 16) = o;
#pragma unroll
      for (int m = 1; m < 64; m <<= 1) sum += __shfl_xor(sum, m, 64);
      if (lane == 0) S[row] = sum;
    }
  } else {
    // ---- colstats: sq[j] += sum_k W^2 ; colsum[j] += sum_k W ----
    const int b = blockIdx.x - 2048;          // 0..255
    const int j = (b & 15) * 256 + threadIdx.x;
    const int k0 = (b >> 4) * 64;
    float a = 0.f, c = 0.f;
#pragma unroll 8
    for (int k = 0; k < 64; ++k) {
      float w = W[(size_t)(k0 + k) * D2 + j];
      a += w * w; c += w;
    }
    atomicAdd(&sq[j], a);
    atomicAdd(&colsum[j], c);
  }
}

// ---- 2. mean-subtracted normalize + transpose to fp8:
// mu[j] = colsum[j]*inv/1024; B8t[j][k] = fp8((W[k][j]*inv - mu[j]) * SCALE_B)
__global__ void convert_b(const float* __restrict__ W, const float* __restrict__ sq,
                          const float* __restrict__ colsum,
                          uchar_t* __restrict__ B8t, float* __restrict__ mu) {
  __shared__ float tile[64][65];
  int t = threadIdx.x;                 // 256
  int j0 = blockIdx.x * 64;            // gridDim.x = 64
  int k0 = blockIdx.y * 64;            // gridDim.y = 16
  int c = t & 63, r4 = t >> 6;
#pragma unroll
  for (int s = 0; s < 16; ++s) {
    int k = s * 4 + r4;
    tile[k][c] = W[(size_t)(k0 + k) * D2 + j0 + c];
  }
  __syncthreads();
#pragma unroll
  for (int s = 0; s < 16; ++s) {
    int jj = s * 4 + r4;
    float inv = 1.0f / sqrtf(sq[j0 + jj]);
    float muj = colsum[j0 + jj] * inv * (1.0f / 1024.0f);
    if (k0 == 0 && c == 0) mu[j0 + jj] = muj;
    float dw = tile[c][jj] * inv - muj;
    B8t[(size_t)(j0 + jj) * D1 + k0 + c] = f32_to_fp8(dw * SCALE_B);
  }
}

// ---- 3. fused fp8 GEMM + exp-sum (R0-VERBATIM: best measured, 228us).
// 128x128 tile, BK=128, 256 thr = 4 waves 2x2, each wave 4x4 of
// mfma_scale_f32_16x16x128_f8f6f4. Double-buffered LDS, one barrier per
// K-iter. dim3(32,256) col-fast grid -> FETCH 133MB (L2 reuse proven).
// Schedule variants (2-phase/3-phase counted vmcnt, R5) measured SLOWER:
// kernel is LDS-read-throughput-bound (~12cy/b128 incl ~4cy conflict tax),
// not barrier-bound.
__global__ __launch_bounds__(256, 2)
void gemm_expsum(const uchar_t* __restrict__ A8, const uchar_t* __restrict__ B8t,
                 const float* __restrict__ S, const float* __restrict__ mu,
                 float* __restrict__ s) {
  __shared__ __align__(16) uchar_t As[2 * 128 * 128];  // 32 KiB
  __shared__ __align__(16) uchar_t Bs[2 * 128 * 128];  // 32 KiB

  const int t = threadIdx.x;
  const int row0 = blockIdx.y * 128;   // gridDim.y = 256
  const int col0 = blockIdx.x * 128;   // gridDim.x = 32 (fast axis)
  const int lane = t & 63;
  const int wave = t >> 6;
  const int wm = (wave >> 1) * 64;
  const int wn = (wave & 1) * 64;
  const int llo = lane & 15, lhi = lane >> 4;

  f32x4 acc[4][4] = {};

  const int srow = t >> 3;
  const int sseg = (t & 7) ^ (srow & 7);
  const uchar_t* gA = A8  + (size_t)(row0 + srow) * D1 + sseg * 16;
  const uchar_t* gB = B8t + (size_t)(col0 + srow) * D1 + sseg * 16;

  const int sw0 = ((lhi * 2 + 0) ^ (llo & 7)) * 16;
  const int sw1 = ((lhi * 2 + 1) ^ (llo & 7)) * 16;

  // prologue: stage tile 0 into buffer 0
#pragma unroll
  for (int i = 0; i < 4; ++i) {
    async_copy16(gA + (size_t)i * 32 * D1, As + t * 16 + i * 4096);
    async_copy16(gB + (size_t)i * 32 * D1, Bs + t * 16 + i * 4096);
  }

  int p = 0;
  for (int kt = 0; kt < D1; kt += 128, p ^= 1) {
    __syncthreads();
    if (kt + 128 < D1) {
#pragma unroll
      for (int i = 0; i < 4; ++i) {
        async_copy16(gA + (size_t)i * 32 * D1 + kt + 128,
                     As + (p ^ 1) * 16384 + t * 16 + i * 4096);
        async_copy16(gB + (size_t)i * 32 * D1 + kt + 128,
                     Bs + (p ^ 1) * 16384 + t * 16 + i * 4096);
      }
    }
    const uchar_t* baseA = As + p * 16384;
    const uchar_t* baseB = Bs + p * 16384;
    i32x8 af[4], bq[4];
#pragma unroll
    for (int mi = 0; mi < 4; ++mi) {
      const uchar_t* q = baseA + (wm + mi * 16 + llo) * 128;
      i32x4 h0 = *(const i32x4*)(q + sw0);
      i32x4 h1 = *(const i32x4*)(q + sw1);
      af[mi] = __builtin_shufflevector(h0, h1, 0, 1, 2, 3, 4, 5, 6, 7);
    }
#pragma unroll
    for (int ni = 0; ni < 4; ++ni) {
      const uchar_t* q = baseB + (wn + ni * 16 + llo) * 128;
      i32x4 h0 = *(const i32x4*)(q + sw0);
      i32x4 h1 = *(const i32x4*)(q + sw1);
      bq[ni] = __builtin_shufflevector(h0, h1, 0, 1, 2, 3, 4, 5, 6, 7);
    }
#pragma unroll
    for (int mi = 0; mi < 4; ++mi)
#pragma unroll
      for (int ni = 0; ni < 4; ++ni)
        acc[mi][ni] = __builtin_amdgcn_mfma_scale_f32_16x16x128_f8f6f4(
            af[mi], bq[ni], acc[mi][ni],
            0, 0, 0, 127, 0, 127);
  }

  // epilogue: x2 = mu_j*S_b + acc*2^-17; per-row sum of exp2(x2*beta*log2e).
  float muv[4];
#pragma unroll
  for (int ni = 0; ni < 4; ++ni) muv[ni] = mu[col0 + wn + ni * 16 + llo];

#pragma unroll
  for (int mi = 0; mi < 4; ++mi) {
    const int row = row0 + wm + mi * 16 + lhi * 4;
    float4 sv = *(const float4*)(S + row);
    float sarr[4] = {sv.x, sv.y, sv.z, sv.w};
    float rs[4];
#pragma unroll
    for (int r = 0; r < 4; ++r) {
      float v = 0.f;
#pragma unroll
      for (int ni = 0; ni < 4; ++ni) {
        float x2 = fmaf(acc[mi][ni][r], INV_SCALE, muv[ni] * sarr[r]);
        v += exp2f(x2 * BETA_LOG2E);
      }
      rs[r] = v;
    }
#pragma unroll
    for (int m = 1; m < 16; m <<= 1) {
#pragma unroll
      for (int r = 0; r < 4; ++r)
        rs[r] += __shfl_xor(rs[r], m, 64);
    }
    if (llo == 0) {
#pragma unroll
      for (int r = 0; r < 4; ++r)
        atomicAdd(&s[row + r], rs[r]);
    }
  }
}

// ---- 4. out[b] = -(1/beta) * log(s[b]) ----
__global__ void finish_kernel(const float* __restrict__ s, float* __restrict__ out) {
  int b = blockIdx.x * 256 + threadIdx.x;
  out[b] = -0.1f * logf(s[b]);
}

extern "C" void kernel_launch(void* const* d_in, const int* in_sizes, int n_in,
                              void* d_out, int out_size, void* d_ws, size_t ws_size,
                              hipStream_t stream) {
  const float* g1 = (const float*)d_in[0];
  const float* W  = (const float*)d_in[1];
  float* out = (float*)d_out;

  char* ws = (char*)d_ws;
  float* s       = (float*)ws;                    // 32768*4 = 131072
  float* sq      = (float*)(ws + 131072);         // 4096*4
  float* colsum  = (float*)(ws + 147456);         // 4096*4
  float* mu      = (float*)(ws + 163840);         // 4096*4
  float* S       = (float*)(ws + 180224);         // 32768*4
  uchar_t* A8    = (uchar_t*)(ws + 311296);       // 32 MiB
  uchar_t* B8t   = (uchar_t*)(ws + 311296 + 33554432);  // 4 MiB

  hipMemsetAsync(ws, 0, 180224, stream);  // zero s, sq, colsum

  prep_fused<<<dim3(2304), 256, 0, stream>>>(g1, A8, S, W, sq, colsum);
  convert_b<<<dim3(64, 16), 256, 0, stream>>>(W, sq, colsum, B8t, mu);
  gemm_expsum<<<dim3(32, 256), 256, 0, stream>>>(A8, B8t, S, mu, s);
  finish_kernel<<<dim3(128), 256, 0, stream>>>(s, out);
}

// Round 8
// 420.529 us; speedup vs baseline: 2.0389x; 1.0035x over previous
//
#include <hip/hip_runtime.h>
#include <hip/hip_bf16.h>
#include <hip/hip_fp8.h>

typedef int i32x8 __attribute__((ext_vector_type(8)));
typedef int i32x4 __attribute__((ext_vector_type(4)));
typedef float f32x4 __attribute__((ext_vector_type(4)));
typedef unsigned char uchar_t;

constexpr int NB = 32768;   // batch rows
constexpr int D1 = 1024;    // K
constexpr int D2 = 4096;    // N
constexpr float BETA_LOG2E = 14.4269504088896340736f; // 10 * log2(e)
constexpr float SCALE_A = 16.0f;        // g1 pre-scale into e4m3 sweet range
constexpr float SCALE_B = 8192.0f;      // dW pre-scale (dW ~ 0.003*N)
constexpr float INV_SCALE = 1.0f / (16.0f * 8192.0f);  // 2^-17

// HW packed f32->fp8 e4m3 (RNE, saturating)
__device__ __forceinline__ uchar_t f32_to_fp8(float f) {
  return (uchar_t)(__builtin_amdgcn_cvt_pk_fp8_f32(f, f, 0, false) & 0xff);
}

__device__ __forceinline__ void async_copy16(const void* g, void* l) {
  __builtin_amdgcn_global_load_lds(
      (const __attribute__((address_space(1))) void*)g,
      (__attribute__((address_space(3))) void*)l, 16, 0, 0);
}

// ---- 1. column stats of W (tiny, runs first so convert_b can merge into
// the big convert kernel): sq[j] += sum_k W^2 ; colsum[j] += sum_k W ----
__global__ void colstats(const float* __restrict__ W, float* __restrict__ sq,
                         float* __restrict__ colsum) {
  int j = blockIdx.x * 256 + threadIdx.x;   // gridDim.x = 16
  int k0 = blockIdx.y * 64;                 // gridDim.y = 16
  float a = 0.f, b = 0.f;
#pragma unroll 8
  for (int k = 0; k < 64; ++k) {
    float w = W[(size_t)(k0 + k) * D2 + j];
    a += w * w; b += w;
  }
  atomicAdd(&sq[j], a);
  atomicAdd(&colsum[j], b);
}

// ---- 2. MERGED convert kernel.
// Blocks 0..2047:  convert_a -- g1 fp32->fp8 + row sums, LANE-CONTIGUOUS
//   loads (lane i reads float4 at byte i*16; wave covers 1KB/instr). All
//   previous variants used 64B-per-lane chunky loads (each dwordx4 touching
//   64 cache lines, 16B used per line) -- suspected 4x transaction
//   amplification capping the 128MB stream at ~800GB/s (aux stuck at ~190us
//   across 3 structural variants). This is the H1-vs-H2 discriminator.
// Blocks 2048..3071: convert_b -- normalize+transpose (needs colstats done;
//   guaranteed by stream order).
__global__ __launch_bounds__(256)
void merged_convert(const float* __restrict__ g1, uchar_t* __restrict__ A8,
                    float* __restrict__ S, const float* __restrict__ W,
                    const float* __restrict__ sq, const float* __restrict__ colsum,
                    uchar_t* __restrict__ B8t, float* __restrict__ mu) {
  __shared__ float tile[64][65];
  if (blockIdx.x < 2048) {
    const int lane = threadIdx.x & 63;
    const int gw = (blockIdx.x * 256 + threadIdx.x) >> 6;  // 8192 waves
    for (int row = gw; row < NB; row += 8192) {
      const float4* src = (const float4*)(g1 + (size_t)row * D1);
      float4 f[4];
#pragma unroll
      for (int c = 0; c < 4; ++c) f[c] = src[c * 64 + lane];  // stride-16B lanes
      float sum = 0.f;
#pragma unroll
      for (int c = 0; c < 4; ++c) sum += f[c].x + f[c].y + f[c].z + f[c].w;
      unsigned ob[4];
#pragma unroll
      for (int c = 0; c < 4; ++c) {
        unsigned w = __builtin_amdgcn_cvt_pk_fp8_f32(f[c].x * SCALE_A,
                                                     f[c].y * SCALE_A, 0, false);
        ob[c] = __builtin_amdgcn_cvt_pk_fp8_f32(f[c].z * SCALE_A,
                                                f[c].w * SCALE_A, w, true);
      }
      // lane's 4 fp8 bytes of chunk c live at col c*256 + lane*4
      unsigned* dst = (unsigned*)(A8 + (size_t)row * D1);
#pragma unroll
      for (int c = 0; c < 4; ++c) dst[c * 64 + lane] = ob[c];
#pragma unroll
      for (int m = 1; m < 64; m <<= 1) sum += __shfl_xor(sum, m, 64);
      if (lane == 0) S[row] = sum;
    }
  } else {
    const int b = blockIdx.x - 2048;     // 0..1023
    const int t = threadIdx.x;
    const int j0 = (b & 63) * 64;
    const int k0 = (b >> 6) * 64;
    const int c = t & 63, r4 = t >> 6;
#pragma unroll
    for (int s = 0; s < 16; ++s) {
      int k = s * 4 + r4;
      tile[k][c] = W[(size_t)(k0 + k) * D2 + j0 + c];
    }
    __syncthreads();
#pragma unroll
    for (int s = 0; s < 16; ++s) {
      int jj = s * 4 + r4;
      float inv = 1.0f / sqrtf(sq[j0 + jj]);
      float muj = colsum[j0 + jj] * inv * (1.0f / 1024.0f);
      if (k0 == 0 && c == 0) mu[j0 + jj] = muj;
      float dw = tile[c][jj] * inv - muj;
      B8t[(size_t)(j0 + jj) * D1 + k0 + c] = f32_to_fp8(dw * SCALE_B);
    }
  }
}

// ---- 3. fused fp8 GEMM + exp-sum (R0-VERBATIM CONTROL: 228us, FETCH 134MB,
// MfmaUtil 26%). 128x128 tile, BK=128, 4 waves 2x2, double-buffered LDS,
// one barrier per K-iter, col-fast dim3(32,256) grid (L2 reuse proven).
// Schedule variants (counted-vmcnt 2/3-phase) and 256^2 tiles all measured
// slower (R2-R6); kernel is LDS-read-throughput-bound.
__global__ __launch_bounds__(256, 2)
void gemm_expsum(const uchar_t* __restrict__ A8, const uchar_t* __restrict__ B8t,
                 const float* __restrict__ S, const float* __restrict__ mu,
                 float* __restrict__ s) {
  __shared__ __align__(16) uchar_t As[2 * 128 * 128];  // 32 KiB
  __shared__ __align__(16) uchar_t Bs[2 * 128 * 128];  // 32 KiB

  const int t = threadIdx.x;
  const int row0 = blockIdx.y * 128;   // gridDim.y = 256
  const int col0 = blockIdx.x * 128;   // gridDim.x = 32 (fast axis)
  const int lane = t & 63;
  const int wave = t >> 6;
  const int wm = (wave >> 1) * 64;
  const int wn = (wave & 1) * 64;
  const int llo = lane & 15, lhi = lane >> 4;

  f32x4 acc[4][4] = {};

  const int srow = t >> 3;
  const int sseg = (t & 7) ^ (srow & 7);
  const uchar_t* gA = A8  + (size_t)(row0 + srow) * D1 + sseg * 16;
  const uchar_t* gB = B8t + (size_t)(col0 + srow) * D1 + sseg * 16;

  const int sw0 = ((lhi * 2 + 0) ^ (llo & 7)) * 16;
  const int sw1 = ((lhi * 2 + 1) ^ (llo & 7)) * 16;

  // prologue: stage tile 0 into buffer 0
#pragma unroll
  for (int i = 0; i < 4; ++i) {
    async_copy16(gA + (size_t)i * 32 * D1, As + t * 16 + i * 4096);
    async_copy16(gB + (size_t)i * 32 * D1, Bs + t * 16 + i * 4096);
  }

  int p = 0;
  for (int kt = 0; kt < D1; kt += 128, p ^= 1) {
    __syncthreads();
    if (kt + 128 < D1) {
#pragma unroll
      for (int i = 0; i < 4; ++i) {
        async_copy16(gA + (size_t)i * 32 * D1 + kt + 128,
                     As + (p ^ 1) * 16384 + t * 16 + i * 4096);
        async_copy16(gB + (size_t)i * 32 * D1 + kt + 128,
                     Bs + (p ^ 1) * 16384 + t * 16 + i * 4096);
      }
    }
    const uchar_t* baseA = As + p * 16384;
    const uchar_t* baseB = Bs + p * 16384;
    i32x8 af[4], bq[4];
#pragma unroll
    for (int mi = 0; mi < 4; ++mi) {
      const uchar_t* q = baseA + (wm + mi * 16 + llo) * 128;
      i32x4 h0 = *(const i32x4*)(q + sw0);
      i32x4 h1 = *(const i32x4*)(q + sw1);
      af[mi] = __builtin_shufflevector(h0, h1, 0, 1, 2, 3, 4, 5, 6, 7);
    }
#pragma unroll
    for (int ni = 0; ni < 4; ++ni) {
      const uchar_t* q = baseB + (wn + ni * 16 + llo) * 128;
      i32x4 h0 = *(const i32x4*)(q + sw0);
      i32x4 h1 = *(const i32x4*)(q + sw1);
      bq[ni] = __builtin_shufflevector(h0, h1, 0, 1, 2, 3, 4, 5, 6, 7);
    }
#pragma unroll
    for (int mi = 0; mi < 4; ++mi)
#pragma unroll
      for (int ni = 0; ni < 4; ++ni)
        acc[mi][ni] = __builtin_amdgcn_mfma_scale_f32_16x16x128_f8f6f4(
            af[mi], bq[ni], acc[mi][ni],
            0, 0, 0, 127, 0, 127);
  }

  // epilogue: x2 = mu_j*S_b + acc*2^-17; per-row sum of exp2(x2*beta*log2e).
  float muv[4];
#pragma unroll
  for (int ni = 0; ni < 4; ++ni) muv[ni] = mu[col0 + wn + ni * 16 + llo];

#pragma unroll
  for (int mi = 0; mi < 4; ++mi) {
    const int row = row0 + wm + mi * 16 + lhi * 4;
    float4 sv = *(const float4*)(S + row);
    float sarr[4] = {sv.x, sv.y, sv.z, sv.w};
    float rs[4];
#pragma unroll
    for (int r = 0; r < 4; ++r) {
      float v = 0.f;
#pragma unroll
      for (int ni = 0; ni < 4; ++ni) {
        float x2 = fmaf(acc[mi][ni][r], INV_SCALE, muv[ni] * sarr[r]);
        v += exp2f(x2 * BETA_LOG2E);
      }
      rs[r] = v;
    }
#pragma unroll
    for (int m = 1; m < 16; m <<= 1) {
#pragma unroll
      for (int r = 0; r < 4; ++r)
        rs[r] += __shfl_xor(rs[r], m, 64);
    }
    if (llo == 0) {
#pragma unroll
      for (int r = 0; r < 4; ++r)
        atomicAdd(&s[row + r], rs[r]);
    }
  }
}

// ---- 4. out[b] = -(1/beta) * log(s[b]) ----
__global__ void finish_kernel(const float* __restrict__ s, float* __restrict__ out) {
  int b = blockIdx.x * 256 + threadIdx.x;
  out[b] = -0.1f * logf(s[b]);
}

extern "C" void kernel_launch(void* const* d_in, const int* in_sizes, int n_in,
                              void* d_out, int out_size, void* d_ws, size_t ws_size,
                              hipStream_t stream) {
  const float* g1 = (const float*)d_in[0];
  const float* W  = (const float*)d_in[1];
  float* out = (float*)d_out;

  char* ws = (char*)d_ws;
  float* s       = (float*)ws;                    // 32768*4 = 131072
  float* sq      = (float*)(ws + 131072);         // 4096*4
  float* colsum  = (float*)(ws + 147456);         // 4096*4
  float* mu      = (float*)(ws + 163840);         // 4096*4
  float* S       = (float*)(ws + 180224);         // 32768*4
  uchar_t* A8    = (uchar_t*)(ws + 311296);       // 32 MiB
  uchar_t* B8t   = (uchar_t*)(ws + 311296 + 33554432);  // 4 MiB

  hipMemsetAsync(ws, 0, 180224, stream);  // zero s, sq, colsum

  colstats<<<dim3(16, 16), 256, 0, stream>>>(W, sq, colsum);
  merged_convert<<<dim3(3072), 256, 0, stream>>>(g1, A8, S, W, sq, colsum, B8t, mu);
  gemm_expsum<<<dim3(32, 256), 256, 0, stream>>>(A8, B8t, S, mu, s);
  finish_kernel<<<dim3(128), 256, 0, stream>>>(s, out);
}